// Round 12
// baseline (233.038 us; speedup 1.0000x reference)
//
#include <hip/hip_runtime.h>

#define N_NODES 100000
#define NBKT 782              // ceil(100000/128) buckets of 128 dst nodes
#define EPB 8192              // edges per partition block
#define NSL 4                 // y1 slices (32 cols = 64B rows: full-line gathers)
#define SL2 1600000           // uints per y1 slice = N_NODES*16

typedef unsigned int uint;
typedef __attribute__((ext_vector_type(8))) short bf16x8;   // 8 bf16 (4 VGPRs)
typedef __attribute__((ext_vector_type(4))) float f32x4;    // MFMA acc

union FragU { uint4 u; bf16x8 b; };

// ---------- bf16 helpers ------------------------------------------------------
__device__ __forceinline__ uint pack_bf16_2(float a, float b) {
    uint ua = __float_as_uint(a), ub = __float_as_uint(b);
    ua += 0x7fff + ((ua >> 16) & 1);           // RNE
    ub += 0x7fff + ((ub >> 16) & 1);
    return (ua >> 16) | (ub & 0xffff0000u);
}
__device__ __forceinline__ float bf_lo(uint u) { return __uint_as_float(u << 16); }
__device__ __forceinline__ float bf_hi(uint u) { return __uint_as_float(u & 0xffff0000u); }

// ---------- edge-index access (handles int32 or raw int64 little-endian) ----
__device__ __forceinline__ int edge_at(const int* __restrict__ ei, int idx, int is64) {
    return is64 ? ei[2 * idx] : ei[idx];
}

// per-block dtype probe: 1 if int64 little-endian layout (all odd words zero)
__device__ __forceinline__ int block_probe_is64(const int* __restrict__ ei, int* sh) {
    int t = threadIdx.x;
    if (t == 0) *sh = 0;
    __syncthreads();
    int any = 0;
    for (int j = t; j < 4096; j += blockDim.x) any |= ei[2 * j + 1];
    if (any) atomicOr(sh, 1);
    __syncthreads();
    return (*sh == 0);
}

// ---------- phase A1: bucket histogram -> private slab; block 0 -> gflag -----
__global__ __launch_bounds__(256) void kA1(const int* __restrict__ ei, int E,
                                           int* __restrict__ slab,
                                           int* __restrict__ gflag) {
    __shared__ int h[NBKT];
    __shared__ int shp;
    int t = threadIdx.x;
    int is64 = block_probe_is64(ei, &shp);
    if (blockIdx.x == 0 && t == 0) gflag[0] = is64 ? 0 : 1;
    for (int i = t; i < NBKT; i += 256) h[i] = 0;
    __syncthreads();
    int base = blockIdx.x * EPB;
    int end = min(base + EPB, E);
    for (int e = base + t; e < end; e += 256) {
        int d = edge_at(ei, E + e, is64);
        atomicAdd(&h[d >> 7], 1);
    }
    __syncthreads();
    for (int i = t; i < NBKT; i += 256)
        slab[(size_t)blockIdx.x * NBKT + i] = h[i];
}

// ---------- phase A2a: column prefix-scan of slab (one wave per bucket) ------
// slab[b][k] <- exclusive prefix over blocks b' < b; bkt_cnt[k] = column total.
// (r10 lesson: parallelize slab traversal across CUs, never one block.)
__global__ __launch_bounds__(256) void kA2a(int* __restrict__ slab, int PB,
                                            int* __restrict__ bkt_cnt) {
    int w = threadIdx.x >> 6;                 // wave in block (0..3)
    int l = threadIdx.x & 63;                 // lane
    int k = blockIdx.x * 4 + w;               // bucket column
    if (k >= NBKT) return;
    int carry = 0;
    for (int base = 0; base < PB; base += 64) {
        int row = base + l;
        int v = (row < PB) ? slab[(size_t)row * NBKT + k] : 0;
        int incl = v;
#pragma unroll
        for (int d = 1; d < 64; d <<= 1) {
            int y = __shfl_up(incl, d, 64);
            if (l >= d) incl += y;
        }
        if (row < PB) slab[(size_t)row * NBKT + k] = carry + incl - v;  // excl
        carry += __shfl(incl, 63, 64);
    }
    if (l == 0) bkt_cnt[k] = carry;
}

// ---------- phase A2b: exclusive scan of 782 bucket counts (1 block, LDS) ----
__global__ __launch_bounds__(1024) void kA2b(const int* __restrict__ bkt_cnt,
                                             int* __restrict__ bkt_off) {
    __shared__ int s[1024];
    int t = threadIdx.x;
    int v = (t < NBKT) ? bkt_cnt[t] : 0;
    s[t] = v;
    __syncthreads();
    for (int d = 1; d < 1024; d <<= 1) {
        int y = (t >= d) ? s[t - d] : 0;
        __syncthreads();
        s[t] += y;
        __syncthreads();
    }
    if (t < NBKT) bkt_off[t] = s[t] - v;       // exclusive
}

// ---------- phase A3: single-pass partition (bases precomputed, no cursors) --
__global__ __launch_bounds__(256) void kA3(const int* __restrict__ ei, int E,
                                           const int* __restrict__ gflag,
                                           const int* __restrict__ slab,
                                           const int* __restrict__ bkt_off,
                                           uint* __restrict__ bkt_data) {
    __shared__ int h[NBKT];                   // local rank cursor
    __shared__ int pre[NBKT];                 // global base for this block
    int t = threadIdx.x;
    int is64 = (gflag[0] == 0);
    for (int i = t; i < NBKT; i += 256) {
        h[i] = 0;
        pre[i] = bkt_off[i] + slab[(size_t)blockIdx.x * NBKT + i];
    }
    __syncthreads();
    int lo = blockIdx.x * EPB;
    int end = min(lo + EPB, E);
    for (int e = lo + t; e < end; e += 256) {
        int d = edge_at(ei, E + e, is64);
        int s = edge_at(ei, e, is64);
        int b = d >> 7;
        int r = atomicAdd(&h[b], 1);
        bkt_data[pre[b] + r] = ((uint)s << 7) | (uint)(d & 127);
    }
}

// ---------- phase B: per-bucket CSR build + degrees + dis + y2 zero ----------
__global__ __launch_bounds__(256) void kB(const uint* __restrict__ bkt_data,
                                          const int* __restrict__ bkt_off,
                                          const int* __restrict__ bkt_cnt,
                                          int* __restrict__ srcs,
                                          int* __restrict__ count,
                                          int* __restrict__ offs,
                                          float* __restrict__ dis,
                                          float* __restrict__ y2) {
    __shared__ int lc[128];    // local degree
    __shared__ int sc[128];    // inclusive scan
    __shared__ int lcur[128];  // local fill cursor
    int t = threadIdx.x;
    int b = blockIdx.x;
    // zero this block's slice of y2 (800000 floats over 782 blocks)
    {
        int zb = b * 1024;
        int ze = min(zb + 1024, N_NODES * 8);
        for (int i = zb + t; i < ze; i += 256) y2[i] = 0.0f;
    }
    if (t < 128) { lc[t] = 0; lcur[t] = 0; }
    __syncthreads();
    int start = bkt_off[b];
    int n = bkt_cnt[b];
    for (int i = t; i < n; i += 256)
        atomicAdd(&lc[bkt_data[start + i] & 127], 1);
    __syncthreads();
    if (t < 128) sc[t] = lc[t];
    __syncthreads();
    for (int d = 1; d < 128; d <<= 1) {
        int y = 0;
        if (t < 128 && t >= d) y = sc[t - d];
        __syncthreads();
        if (t < 128) sc[t] += y;
        __syncthreads();
    }
    if (t < 128) {
        int node = b * 128 + t;
        if (node < N_NODES) {
            int c = lc[t];
            count[node] = c;
            offs[node] = start + sc[t] - c;
            dis[node] = rsqrtf((float)c + 1.0f);
        }
    }
    __syncthreads();
    for (int i = t; i < n; i += 256) {
        uint rec = bkt_data[start + i];
        int dl = rec & 127;
        int r = atomicAdd(&lcur[dl], 1);
        srcs[start + (sc[dl] - lc[dl]) + r] = rec >> 7;
    }
}

// ---------- GEMM1 (MFMA bf16): y1s = bf16((x @ W1) * dis)  4-slice layout ----
// Block = 64 rows, 4 waves x 16 rows. LDS: W1^T bf16, 16B-XOR swizzled.
// Slice = 32 cols (64B rows). Plain loads/stores (NT regressed, r9).
__global__ __launch_bounds__(256) void k_gemm1(const float* __restrict__ x,
                                               const float* __restrict__ W,
                                               const float* __restrict__ dis,
                                               uint* __restrict__ y1s) {
    __shared__ uint4 WtA[2048];               // 32 KB
    char* wt = (char*)WtA;
    int t = threadIdx.x;

    const float4* W4 = (const float4*)W;
#pragma unroll
    for (int ii = 0; ii < 4; ++ii) {
        int tile = t + 256 * ii;              // 1024 (nq,kq) 4x4 tiles
        int nq = tile >> 5, kq = tile & 31;
        float4 r0 = W4[(4 * kq + 0) * 32 + nq];
        float4 r1 = W4[(4 * kq + 1) * 32 + nq];
        float4 r2 = W4[(4 * kq + 2) * 32 + nq];
        float4 r3 = W4[(4 * kq + 3) * 32 + nq];
        const float* p0 = (const float*)&r0;
        const float* p1 = (const float*)&r1;
        const float* p2 = (const float*)&r2;
        const float* p3 = (const float*)&r3;
#pragma unroll
        for (int cc = 0; cc < 4; ++cc) {
            int n = 4 * nq + cc;
            uint2 v;
            v.x = pack_bf16_2(p0[cc], p1[cc]);
            v.y = pack_bf16_2(p2[cc], p3[cc]);
            *(uint2*)(wt + n * 256 + (((kq >> 1) ^ (n & 7)) << 4) + ((kq & 1) << 3)) = v;
        }
    }
    __syncthreads();

    int w = t >> 6, lane = t & 63;
    int m = lane & 15, kg = lane >> 4;
    int row0 = blockIdx.x * 64 + 16 * w;

    int arow = row0 + m;
    bool av = arow < N_NODES;
    const float4* xr = (const float4*)(x + (size_t)arow * 128);
    float4 z4 = make_float4(0.f, 0.f, 0.f, 0.f);
    FragU af[4];
#pragma unroll
    for (int kf = 0; kf < 4; ++kf) {
        float4 g0 = av ? xr[8 * kf + 2 * kg]     : z4;
        float4 g1 = av ? xr[8 * kf + 2 * kg + 1] : z4;
        const float* a0 = (const float*)&g0;
        const float* a1 = (const float*)&g1;
        af[kf].u.x = pack_bf16_2(a0[0], a0[1]);
        af[kf].u.y = pack_bf16_2(a0[2], a0[3]);
        af[kf].u.z = pack_bf16_2(a1[0], a1[1]);
        af[kf].u.w = pack_bf16_2(a1[2], a1[3]);
    }

    int crow = row0 + 4 * kg;
    float dd[4];
#pragma unroll
    for (int rr = 0; rr < 4; ++rr)
        dd[rr] = (crow + rr < N_NODES) ? dis[crow + rr] : 0.0f;

#pragma unroll
    for (int ct = 0; ct < 8; ++ct) {          // 16-col tile; slice = ct>>1
        f32x4 acc = {0.f, 0.f, 0.f, 0.f};
#pragma unroll
        for (int kf = 0; kf < 4; ++kf) {
            int n = 16 * ct + m;              // B col = lane&15
            bf16x8 bw = *(const bf16x8*)(wt + n * 256 + ((((kf << 2) | kg) ^ (n & 7)) << 4));
            acc = __builtin_amdgcn_mfma_f32_16x16x32_bf16(af[kf].b, bw, acc, 0, 0, 0);
        }
#pragma unroll
        for (int rr = 0; rr < 4; ++rr) {
            float v = acc[rr] * dd[rr];
            float p = __shfl_xor(v, 1, 64);   // partner col (odd)
            if (!(lane & 1)) {
                int grow = crow + rr;
                if (grow < N_NODES)
                    y1s[(size_t)(ct >> 1) * SL2 + grow * 16 + (ct & 1) * 8 + (m >> 1)]
                        = pack_bf16_2(v, p);
            }
        }
    }
}

// ---------- Aggregation 1 (4-slice, full-line gathers) + partial GEMM2 -------
// slice = blockIdx.x % 4. 8-lane group per node, EDGE-PER-LANE; each edge
// loads one full 64B row (4x dwordx4 -> 1 L1 line-fill, no waste).
// (r6/r7: keep 1-edge-deep; r9: no NT.)
__global__ __launch_bounds__(256) void k_agg1s(const uint* __restrict__ y1s,
                                               const int* __restrict__ srcs,
                                               const int* __restrict__ offs,
                                               const int* __restrict__ count,
                                               const float* __restrict__ dis,
                                               const float* __restrict__ b1,
                                               const float* __restrict__ W2,
                                               float* __restrict__ y2) {
    int t = threadIdx.x;
    int slice = blockIdx.x & 3;
    int nb = blockIdx.x >> 2;
    int g = t >> 3;                    // group 0..31
    int j = t & 7;                     // lane in group
    int d = nb * 32 + g;               // node (3125*32 == 100000)

    const uint4* ybase = (const uint4*)(y1s + (size_t)slice * SL2);
    float acc[32];
#pragma unroll
    for (int c = 0; c < 32; ++c) acc[c] = 0.0f;

    int st = offs[d], n = count[d];
    for (int i = j; i <= n; i += 8) {            // i==n -> self-loop (one lane)
        int sk = d;
        if (i < n) sk = srcs[st + i];
        uint4 q0 = ybase[(size_t)sk * 4];
        uint4 q1 = ybase[(size_t)sk * 4 + 1];
        uint4 q2 = ybase[(size_t)sk * 4 + 2];
        uint4 q3 = ybase[(size_t)sk * 4 + 3];
        acc[0]  += bf_lo(q0.x); acc[1]  += bf_hi(q0.x);
        acc[2]  += bf_lo(q0.y); acc[3]  += bf_hi(q0.y);
        acc[4]  += bf_lo(q0.z); acc[5]  += bf_hi(q0.z);
        acc[6]  += bf_lo(q0.w); acc[7]  += bf_hi(q0.w);
        acc[8]  += bf_lo(q1.x); acc[9]  += bf_hi(q1.x);
        acc[10] += bf_lo(q1.y); acc[11] += bf_hi(q1.y);
        acc[12] += bf_lo(q1.z); acc[13] += bf_hi(q1.z);
        acc[14] += bf_lo(q1.w); acc[15] += bf_hi(q1.w);
        acc[16] += bf_lo(q2.x); acc[17] += bf_hi(q2.x);
        acc[18] += bf_lo(q2.y); acc[19] += bf_hi(q2.y);
        acc[20] += bf_lo(q2.z); acc[21] += bf_hi(q2.z);
        acc[22] += bf_lo(q2.w); acc[23] += bf_hi(q2.w);
        acc[24] += bf_lo(q3.x); acc[25] += bf_hi(q3.x);
        acc[26] += bf_lo(q3.y); acc[27] += bf_hi(q3.y);
        acc[28] += bf_lo(q3.z); acc[29] += bf_hi(q3.z);
        acc[30] += bf_lo(q3.w); acc[31] += bf_hi(q3.w);
    }

    // reduce-scatter 32 -> 4: lane j ends with cols 4j..4j+3
    int hi4 = (j >> 2) & 1, hi2 = (j >> 1) & 1, hi1 = j & 1;
    float v16[16];
#pragma unroll
    for (int c = 0; c < 16; ++c) {
        float keep = hi4 ? acc[c + 16] : acc[c];
        float send = hi4 ? acc[c] : acc[c + 16];
        v16[c] = keep + __shfl_xor(send, 4, 8);
    }
    float v8[8];
#pragma unroll
    for (int c = 0; c < 8; ++c) {
        float keep = hi2 ? v16[c + 8] : v16[c];
        float send = hi2 ? v16[c] : v16[c + 8];
        v8[c] = keep + __shfl_xor(send, 2, 8);
    }
    float v4[4];
#pragma unroll
    for (int c = 0; c < 4; ++c) {
        float keep = hi1 ? v8[c + 4] : v8[c];
        float send = hi1 ? v8[c] : v8[c + 4];
        v4[c] = keep + __shfl_xor(send, 1, 8);
    }

    float ddv = dis[d];
    float4 bv = ((const float4*)b1)[slice * 8 + j];
    float h0 = fmaxf(fmaf(v4[0], ddv, bv.x), 0.0f);
    float h1 = fmaxf(fmaf(v4[1], ddv, bv.y), 0.0f);
    float h2 = fmaxf(fmaf(v4[2], ddv, bv.z), 0.0f);
    float h3 = fmaxf(fmaf(v4[3], ddv, bv.w), 0.0f);

    // partial GEMM2: 4 W2 rows (epilogue load), then class reduce-scatter
    const float* wr = W2 + (size_t)(slice * 32 + 4 * j) * 8;
    float p[8];
#pragma unroll
    for (int c = 0; c < 8; ++c)
        p[c] = h0 * wr[c] + h1 * wr[8 + c] + h2 * wr[16 + c] + h3 * wr[24 + c];
    float q4[4];
#pragma unroll
    for (int c = 0; c < 4; ++c) {
        float keep = hi4 ? p[c + 4] : p[c];
        float send = hi4 ? p[c] : p[c + 4];
        q4[c] = keep + __shfl_xor(send, 4, 8);
    }
    float q2[2];
#pragma unroll
    for (int c = 0; c < 2; ++c) {
        float keep = hi2 ? q4[c + 2] : q4[c];
        float send = hi2 ? q4[c] : q4[c + 2];
        q2[c] = keep + __shfl_xor(send, 2, 8);
    }
    float keep = hi1 ? q2[1] : q2[0];
    float send = hi1 ? q2[0] : q2[1];
    float q = keep + __shfl_xor(send, 1, 8);   // class j

    atomicAdd(&y2[(size_t)d * 8 + j], q * ddv);
}

// ---------- Aggregation 2 + bias + log_softmax -> out ------------------------
__global__ __launch_bounds__(256) void k_agg2(const float* __restrict__ y2,
                                              const int* __restrict__ srcs,
                                              const int* __restrict__ offs,
                                              const int* __restrict__ count,
                                              const float* __restrict__ dis,
                                              const float* __restrict__ b2,
                                              float* __restrict__ out) {
    int g = (blockIdx.x * 256 + threadIdx.x) >> 3;   // node
    int c = threadIdx.x & 7;                         // class
    if (g >= N_NODES) return;
    float acc = y2[(size_t)g * 8 + c];               // self-loop term
    float acc2 = 0.0f;
    int st = offs[g], n = count[g];
    int i = 0;
    for (; i + 2 <= n; i += 2) {
        int s0 = srcs[st + i], s1 = srcs[st + i + 1];
        acc  += y2[(size_t)s0 * 8 + c];
        acc2 += y2[(size_t)s1 * 8 + c];
    }
    if (i < n) acc += y2[(size_t)srcs[st + i] * 8 + c];
    acc += acc2;

    float o = fmaf(acc, dis[g], b2[c]);
    float m = o;
#pragma unroll
    for (int k = 1; k < 8; k <<= 1) m = fmaxf(m, __shfl_xor(m, k, 64));
    float e = expf(o - m);
    float ssum = e;
#pragma unroll
    for (int k = 1; k < 8; k <<= 1) ssum += __shfl_xor(ssum, k, 64);
    out[(size_t)g * 8 + c] = (o - m) - logf(ssum);
}

// ---------- host launcher -----------------------------------------------------
extern "C" void kernel_launch(void* const* d_in, const int* in_sizes, int n_in,
                              void* d_out, int out_size, void* d_ws, size_t ws_size,
                              hipStream_t stream) {
    const float* x  = (const float*)d_in[0];
    const int*   ei = (const int*)d_in[1];
    const float* W1 = (const float*)d_in[2];
    const float* b1 = (const float*)d_in[3];
    const float* W2 = (const float*)d_in[4];
    const float* b2 = (const float*)d_in[5];
    float* out = (float*)d_out;
    const int E = in_sizes[1] / 2;     // logical edge count
    const int PB = (E + EPB - 1) / EPB;
    const int Epad = (E + 3) & ~3;
    int slabInts = (PB * NBKT + 3) & ~3;

    // workspace layout (all 16B-aligned)
    int*   slab     = (int*)d_ws;                      // PB*NBKT ints
    int*   bkt_cnt  = slab + slabInts;                 // 784 ints
    int*   bkt_off  = bkt_cnt + 784;                   // 784 ints
    int*   gflag    = bkt_off + 784;                   // 4 ints
    int*   count    = gflag + 4;                       // N ints
    int*   offs     = count + N_NODES;                 // N ints
    float* dis      = (float*)(offs + N_NODES);        // N floats
    uint*  bkt_data = (uint*)(dis + N_NODES);          // Epad uints
    int*   srcs     = (int*)(bkt_data + Epad);         // Epad ints
    uint*  y1s      = (uint*)(srcs + Epad);            // 4 slices * N*16 uints
    float* y2       = (float*)(y1s + (size_t)NSL * SL2);  // N*8 floats

    kA1    <<<PB, 256, 0, stream>>>(ei, E, slab, gflag);
    kA2a   <<<(NBKT + 3) / 4, 256, 0, stream>>>(slab, PB, bkt_cnt);
    kA2b   <<<1, 1024, 0, stream>>>(bkt_cnt, bkt_off);
    kA3    <<<PB, 256, 0, stream>>>(ei, E, gflag, slab, bkt_off, bkt_data);
    kB     <<<NBKT, 256, 0, stream>>>(bkt_data, bkt_off, bkt_cnt, srcs, count, offs, dis, y2);

    k_gemm1<<<(N_NODES + 63) / 64, 256, 0, stream>>>(x, W1, dis, y1s);
    k_agg1s<<<NSL * 3125, 256, 0, stream>>>(y1s, srcs, offs, count, dis, b1, W2, y2);
    k_agg2 <<<(N_NODES + 31) / 32, 256, 0, stream>>>(y2, srcs, offs, count, dis, b2, out);
}

// Round 13
// 218.849 us; speedup vs baseline: 1.0648x; 1.0648x over previous
//
#include <hip/hip_runtime.h>

#define N_NODES 100000
#define NBKT 782              // ceil(100000/128) buckets of 128 dst nodes
#define EPB 8192              // edges per partition block
#define SL_STRIDE 800000      // uints per y1 slice = N_NODES*8

typedef unsigned int uint;
typedef __attribute__((ext_vector_type(8))) short bf16x8;   // 8 bf16 (4 VGPRs)
typedef __attribute__((ext_vector_type(4))) float f32x4;    // MFMA acc

union FragU { uint4 u; bf16x8 b; };

// ---------- bf16 helpers ------------------------------------------------------
__device__ __forceinline__ uint pack_bf16_2(float a, float b) {
    uint ua = __float_as_uint(a), ub = __float_as_uint(b);
    ua += 0x7fff + ((ua >> 16) & 1);           // RNE
    ub += 0x7fff + ((ub >> 16) & 1);
    return (ua >> 16) | (ub & 0xffff0000u);
}
__device__ __forceinline__ float bf_lo(uint u) { return __uint_as_float(u << 16); }
__device__ __forceinline__ float bf_hi(uint u) { return __uint_as_float(u & 0xffff0000u); }

// ---------- edge-index access (handles int32 or raw int64 little-endian) ----
__device__ __forceinline__ int edge_at(const int* __restrict__ ei, int idx, int is64) {
    return is64 ? ei[2 * idx] : ei[idx];
}

// per-block dtype probe: 1 if int64 little-endian layout (all odd words zero)
__device__ __forceinline__ int block_probe_is64(const int* __restrict__ ei, int* sh) {
    int t = threadIdx.x;
    if (t == 0) *sh = 0;
    __syncthreads();
    int any = 0;
    for (int j = t; j < 4096; j += blockDim.x) any |= ei[2 * j + 1];
    if (any) atomicOr(sh, 1);
    __syncthreads();
    return (*sh == 0);
}

// ---------- phase A1: bucket histogram -> private slab; block 0 -> gflag -----
__global__ __launch_bounds__(256) void kA1(const int* __restrict__ ei, int E,
                                           int* __restrict__ slab,
                                           int* __restrict__ gflag) {
    __shared__ int h[NBKT];
    __shared__ int shp;
    int t = threadIdx.x;
    int is64 = block_probe_is64(ei, &shp);
    if (blockIdx.x == 0 && t == 0) gflag[0] = is64 ? 0 : 1;
    for (int i = t; i < NBKT; i += 256) h[i] = 0;
    __syncthreads();
    int base = blockIdx.x * EPB;
    int end = min(base + EPB, E);
    for (int e = base + t; e < end; e += 256) {
        int d = edge_at(ei, E + e, is64);
        atomicAdd(&h[d >> 7], 1);
    }
    __syncthreads();
    for (int i = t; i < NBKT; i += 256)
        slab[(size_t)blockIdx.x * NBKT + i] = h[i];
}

// ---------- phase A2a: column prefix-scan of slab (one wave per bucket) ------
// slab[b][k] <- exclusive prefix over blocks b' < b; bkt_cnt[k] = column total.
// (r10 lesson: parallelize slab traversal across CUs, never one block.)
__global__ __launch_bounds__(256) void kA2a(int* __restrict__ slab, int PB,
                                            int* __restrict__ bkt_cnt) {
    int w = threadIdx.x >> 6;                 // wave in block (0..3)
    int l = threadIdx.x & 63;                 // lane
    int k = blockIdx.x * 4 + w;               // bucket column
    if (k >= NBKT) return;
    int carry = 0;
    for (int base = 0; base < PB; base += 64) {
        int row = base + l;
        int v = (row < PB) ? slab[(size_t)row * NBKT + k] : 0;
        int incl = v;
#pragma unroll
        for (int d = 1; d < 64; d <<= 1) {
            int y = __shfl_up(incl, d, 64);
            if (l >= d) incl += y;
        }
        if (row < PB) slab[(size_t)row * NBKT + k] = carry + incl - v;  // excl
        carry += __shfl(incl, 63, 64);
    }
    if (l == 0) bkt_cnt[k] = carry;
}

// ---------- phase A2b: exclusive scan of 782 bucket counts (1 block, LDS) ----
__global__ __launch_bounds__(1024) void kA2b(const int* __restrict__ bkt_cnt,
                                             int* __restrict__ bkt_off) {
    __shared__ int s[1024];
    int t = threadIdx.x;
    int v = (t < NBKT) ? bkt_cnt[t] : 0;
    s[t] = v;
    __syncthreads();
    for (int d = 1; d < 1024; d <<= 1) {
        int y = (t >= d) ? s[t - d] : 0;
        __syncthreads();
        s[t] += y;
        __syncthreads();
    }
    if (t < NBKT) bkt_off[t] = s[t] - v;       // exclusive
}

// ---------- phase A3: single-pass partition (bases precomputed, no cursors) --
__global__ __launch_bounds__(256) void kA3(const int* __restrict__ ei, int E,
                                           const int* __restrict__ gflag,
                                           const int* __restrict__ slab,
                                           const int* __restrict__ bkt_off,
                                           uint* __restrict__ bkt_data) {
    __shared__ int h[NBKT];                   // local rank cursor
    __shared__ int pre[NBKT];                 // global base for this block
    int t = threadIdx.x;
    int is64 = (gflag[0] == 0);
    for (int i = t; i < NBKT; i += 256) {
        h[i] = 0;
        pre[i] = bkt_off[i] + slab[(size_t)blockIdx.x * NBKT + i];
    }
    __syncthreads();
    int lo = blockIdx.x * EPB;
    int end = min(lo + EPB, E);
    for (int e = lo + t; e < end; e += 256) {
        int d = edge_at(ei, E + e, is64);
        int s = edge_at(ei, e, is64);
        int b = d >> 7;
        int r = atomicAdd(&h[b], 1);
        bkt_data[pre[b] + r] = ((uint)s << 7) | (uint)(d & 127);
    }
}

// ---------- phase B: per-bucket CSR build + degrees + dis + y2 zero ----------
__global__ __launch_bounds__(256) void kB(const uint* __restrict__ bkt_data,
                                          const int* __restrict__ bkt_off,
                                          const int* __restrict__ bkt_cnt,
                                          int* __restrict__ srcs,
                                          int* __restrict__ count,
                                          int* __restrict__ offs,
                                          float* __restrict__ dis,
                                          float* __restrict__ y2) {
    __shared__ int lc[128];    // local degree
    __shared__ int sc[128];    // inclusive scan
    __shared__ int lcur[128];  // local fill cursor
    int t = threadIdx.x;
    int b = blockIdx.x;
    // zero this block's slice of y2 (800000 floats over 782 blocks)
    {
        int zb = b * 1024;
        int ze = min(zb + 1024, N_NODES * 8);
        for (int i = zb + t; i < ze; i += 256) y2[i] = 0.0f;
    }
    if (t < 128) { lc[t] = 0; lcur[t] = 0; }
    __syncthreads();
    int start = bkt_off[b];
    int n = bkt_cnt[b];
    for (int i = t; i < n; i += 256)
        atomicAdd(&lc[bkt_data[start + i] & 127], 1);
    __syncthreads();
    if (t < 128) sc[t] = lc[t];
    __syncthreads();
    for (int d = 1; d < 128; d <<= 1) {
        int y = 0;
        if (t < 128 && t >= d) y = sc[t - d];
        __syncthreads();
        if (t < 128) sc[t] += y;
        __syncthreads();
    }
    if (t < 128) {
        int node = b * 128 + t;
        if (node < N_NODES) {
            int c = lc[t];
            count[node] = c;
            offs[node] = start + sc[t] - c;
            dis[node] = rsqrtf((float)c + 1.0f);
        }
    }
    __syncthreads();
    for (int i = t; i < n; i += 256) {
        uint rec = bkt_data[start + i];
        int dl = rec & 127;
        int r = atomicAdd(&lcur[dl], 1);
        srcs[start + (sc[dl] - lc[dl]) + r] = rec >> 7;
    }
}

// ---------- GEMM1 (MFMA bf16): y1s = bf16((x @ W1) * dis)  8-slice layout ----
// (r12 lesson: slice MUST fit a 4MB XCD L2 — 8 x 3.2MB, never 4 x 6.4MB.)
__global__ __launch_bounds__(256) void k_gemm1(const float* __restrict__ x,
                                               const float* __restrict__ W,
                                               const float* __restrict__ dis,
                                               uint* __restrict__ y1s) {
    __shared__ uint4 WtA[2048];               // 32 KB
    char* wt = (char*)WtA;
    int t = threadIdx.x;

    const float4* W4 = (const float4*)W;
#pragma unroll
    for (int ii = 0; ii < 4; ++ii) {
        int tile = t + 256 * ii;              // 1024 (nq,kq) 4x4 tiles
        int nq = tile >> 5, kq = tile & 31;
        float4 r0 = W4[(4 * kq + 0) * 32 + nq];
        float4 r1 = W4[(4 * kq + 1) * 32 + nq];
        float4 r2 = W4[(4 * kq + 2) * 32 + nq];
        float4 r3 = W4[(4 * kq + 3) * 32 + nq];
        const float* p0 = (const float*)&r0;
        const float* p1 = (const float*)&r1;
        const float* p2 = (const float*)&r2;
        const float* p3 = (const float*)&r3;
#pragma unroll
        for (int cc = 0; cc < 4; ++cc) {
            int n = 4 * nq + cc;
            uint2 v;
            v.x = pack_bf16_2(p0[cc], p1[cc]);
            v.y = pack_bf16_2(p2[cc], p3[cc]);
            *(uint2*)(wt + n * 256 + (((kq >> 1) ^ (n & 7)) << 4) + ((kq & 1) << 3)) = v;
        }
    }
    __syncthreads();

    int w = t >> 6, lane = t & 63;
    int m = lane & 15, kg = lane >> 4;
    int row0 = blockIdx.x * 64 + 16 * w;

    int arow = row0 + m;
    bool av = arow < N_NODES;
    const float4* xr = (const float4*)(x + (size_t)arow * 128);
    float4 z4 = make_float4(0.f, 0.f, 0.f, 0.f);
    FragU af[4];
#pragma unroll
    for (int kf = 0; kf < 4; ++kf) {
        float4 g0 = av ? xr[8 * kf + 2 * kg]     : z4;
        float4 g1 = av ? xr[8 * kf + 2 * kg + 1] : z4;
        const float* a0 = (const float*)&g0;
        const float* a1 = (const float*)&g1;
        af[kf].u.x = pack_bf16_2(a0[0], a0[1]);
        af[kf].u.y = pack_bf16_2(a0[2], a0[3]);
        af[kf].u.z = pack_bf16_2(a1[0], a1[1]);
        af[kf].u.w = pack_bf16_2(a1[2], a1[3]);
    }

    int crow = row0 + 4 * kg;
    float dd[4];
#pragma unroll
    for (int rr = 0; rr < 4; ++rr)
        dd[rr] = (crow + rr < N_NODES) ? dis[crow + rr] : 0.0f;

#pragma unroll
    for (int ct = 0; ct < 8; ++ct) {          // col-tile == slice
        f32x4 acc = {0.f, 0.f, 0.f, 0.f};
#pragma unroll
        for (int kf = 0; kf < 4; ++kf) {
            int n = 16 * ct + m;              // B col = lane&15
            bf16x8 bw = *(const bf16x8*)(wt + n * 256 + ((((kf << 2) | kg) ^ (n & 7)) << 4));
            acc = __builtin_amdgcn_mfma_f32_16x16x32_bf16(af[kf].b, bw, acc, 0, 0, 0);
        }
#pragma unroll
        for (int rr = 0; rr < 4; ++rr) {
            float v = acc[rr] * dd[rr];
            float p = __shfl_xor(v, 1, 64);   // partner col (odd)
            if (!(lane & 1)) {
                int grow = crow + rr;
                if (grow < N_NODES)
                    y1s[(size_t)ct * SL_STRIDE + grow * 8 + (m >> 1)] = pack_bf16_2(v, p);
            }
        }
    }
}

// ---------- Aggregation 1 (8-slice, XCD-local L2) + partial GEMM2 ------------
// slice = blockIdx.x % 8. 8-lane group per node, EDGE-PER-LANE, 2x dwordx4.
// (r6 config, 100us floor: 32 VGPR / 76% occ. r7: no deeper unroll; r9: no NT;
//  r12: slice must stay < 4MB L2.)
__global__ __launch_bounds__(256) void k_agg1s(const uint* __restrict__ y1s,
                                               const int* __restrict__ srcs,
                                               const int* __restrict__ offs,
                                               const int* __restrict__ count,
                                               const float* __restrict__ dis,
                                               const float* __restrict__ b1,
                                               const float* __restrict__ W2,
                                               float* __restrict__ y2) {
    int t = threadIdx.x;
    int slice = blockIdx.x & 7;
    int nb = blockIdx.x >> 3;
    int g = t >> 3;                    // group 0..31
    int j = t & 7;                     // lane in group
    int d = nb * 32 + g;               // node (3125*32 == 100000)

    // W2 rows for this lane (fixed): rows slice*16+2j, slice*16+2j+1
    float w0[8], w1[8];
    const float* wr0 = W2 + (size_t)(slice * 16 + 2 * j) * 8;
#pragma unroll
    for (int c = 0; c < 8; ++c) { w0[c] = wr0[c]; w1[c] = wr0[8 + c]; }

    const uint4* ybase = (const uint4*)(y1s + (size_t)slice * SL_STRIDE);
    float acc[16];
#pragma unroll
    for (int c = 0; c < 16; ++c) acc[c] = 0.0f;

    int st = offs[d], n = count[d];
    for (int i = j; i <= n; i += 8) {            // i==n -> self-loop (one lane)
        int sk = d;
        if (i < n) sk = srcs[st + i];
        uint4 a  = ybase[(size_t)sk * 2];
        uint4 bq = ybase[(size_t)sk * 2 + 1];
        acc[0]  += bf_lo(a.x);  acc[1]  += bf_hi(a.x);
        acc[2]  += bf_lo(a.y);  acc[3]  += bf_hi(a.y);
        acc[4]  += bf_lo(a.z);  acc[5]  += bf_hi(a.z);
        acc[6]  += bf_lo(a.w);  acc[7]  += bf_hi(a.w);
        acc[8]  += bf_lo(bq.x); acc[9]  += bf_hi(bq.x);
        acc[10] += bf_lo(bq.y); acc[11] += bf_hi(bq.y);
        acc[12] += bf_lo(bq.z); acc[13] += bf_hi(bq.z);
        acc[14] += bf_lo(bq.w); acc[15] += bf_hi(bq.w);
    }

    // reduce-scatter: lane j ends with cols 2j (v2[0]) and 2j+1 (v2[1])
    int hi4 = (j >> 2) & 1, hi2 = (j >> 1) & 1, hi1 = j & 1;
    float v8[8];
#pragma unroll
    for (int c = 0; c < 8; ++c) {
        float keep = hi4 ? acc[c + 8] : acc[c];
        float send = hi4 ? acc[c] : acc[c + 8];
        v8[c] = keep + __shfl_xor(send, 4, 8);
    }
    float v4[4];
#pragma unroll
    for (int c = 0; c < 4; ++c) {
        float keep = hi2 ? v8[c + 4] : v8[c];
        float send = hi2 ? v8[c] : v8[c + 4];
        v4[c] = keep + __shfl_xor(send, 2, 8);
    }
    float v2[2];
#pragma unroll
    for (int c = 0; c < 2; ++c) {
        float keep = hi1 ? v4[c + 2] : v4[c];
        float send = hi1 ? v4[c] : v4[c + 2];
        v2[c] = keep + __shfl_xor(send, 1, 8);
    }

    float ddv = dis[d];
    float2 b = ((const float2*)b1)[slice * 8 + j];
    float h0 = fmaxf(fmaf(v2[0], ddv, b.x), 0.0f);
    float h1 = fmaxf(fmaf(v2[1], ddv, b.y), 0.0f);

    float p[8];
#pragma unroll
    for (int c = 0; c < 8; ++c) p[c] = h0 * w0[c] + h1 * w1[c];
    float q4[4];
#pragma unroll
    for (int c = 0; c < 4; ++c) {
        float keep = hi4 ? p[c + 4] : p[c];
        float send = hi4 ? p[c] : p[c + 4];
        q4[c] = keep + __shfl_xor(send, 4, 8);
    }
    float q2[2];
#pragma unroll
    for (int c = 0; c < 2; ++c) {
        float keep = hi2 ? q4[c + 2] : q4[c];
        float send = hi2 ? q4[c] : q4[c + 2];
        q2[c] = keep + __shfl_xor(send, 2, 8);
    }
    float keep = hi1 ? q2[1] : q2[0];
    float send = hi1 ? q2[0] : q2[1];
    float q = keep + __shfl_xor(send, 1, 8);   // class j

    atomicAdd(&y2[(size_t)d * 8 + j], q * ddv);
}

// ---------- Aggregation 2 (edge-per-lane) + bias + log_softmax -> out --------
// 8-lane group per node; lane j owns edges i = j mod 8, loads full 32B y2 row
// (2 requests/edge vs 8 with class-per-lane). Self-loop = virtual edge i==n.
__global__ __launch_bounds__(256) void k_agg2(const float* __restrict__ y2,
                                              const int* __restrict__ srcs,
                                              const int* __restrict__ offs,
                                              const int* __restrict__ count,
                                              const float* __restrict__ dis,
                                              const float* __restrict__ b2,
                                              float* __restrict__ out) {
    int t = threadIdx.x;
    int g = (blockIdx.x * 256 + t) >> 3;   // node
    int j = t & 7;                         // lane in group
    if (g >= N_NODES) return;
    const float4* yb = (const float4*)y2;
    float acc[8];
#pragma unroll
    for (int c = 0; c < 8; ++c) acc[c] = 0.0f;
    int st = offs[g], n = count[g];
    for (int i = j; i <= n; i += 8) {          // i==n -> self term (one lane)
        int sk = g;
        if (i < n) sk = srcs[st + i];
        float4 a = yb[(size_t)sk * 2];
        float4 b = yb[(size_t)sk * 2 + 1];
        acc[0] += a.x; acc[1] += a.y; acc[2] += a.z; acc[3] += a.w;
        acc[4] += b.x; acc[5] += b.y; acc[6] += b.z; acc[7] += b.w;
    }
    // reduce-scatter 8 -> 1: lane j ends with class j
    int hi4 = (j >> 2) & 1, hi2 = (j >> 1) & 1, hi1 = j & 1;
    float v4[4];
#pragma unroll
    for (int c = 0; c < 4; ++c) {
        float keep = hi4 ? acc[c + 4] : acc[c];
        float send = hi4 ? acc[c] : acc[c + 4];
        v4[c] = keep + __shfl_xor(send, 4, 8);
    }
    float v2[2];
#pragma unroll
    for (int c = 0; c < 2; ++c) {
        float keep = hi2 ? v4[c + 2] : v4[c];
        float send = hi2 ? v4[c] : v4[c + 2];
        v2[c] = keep + __shfl_xor(send, 2, 8);
    }
    float keep = hi1 ? v2[1] : v2[0];
    float send = hi1 ? v2[0] : v2[1];
    float q = keep + __shfl_xor(send, 1, 8);   // class j

    float o = fmaf(q, dis[g], b2[j]);
    float m = o;
#pragma unroll
    for (int k = 1; k < 8; k <<= 1) m = fmaxf(m, __shfl_xor(m, k, 64));
    float e = expf(o - m);
    float ssum = e;
#pragma unroll
    for (int k = 1; k < 8; k <<= 1) ssum += __shfl_xor(ssum, k, 64);
    out[(size_t)g * 8 + j] = (o - m) - logf(ssum);
}

// ---------- host launcher -----------------------------------------------------
extern "C" void kernel_launch(void* const* d_in, const int* in_sizes, int n_in,
                              void* d_out, int out_size, void* d_ws, size_t ws_size,
                              hipStream_t stream) {
    const float* x  = (const float*)d_in[0];
    const int*   ei = (const int*)d_in[1];
    const float* W1 = (const float*)d_in[2];
    const float* b1 = (const float*)d_in[3];
    const float* W2 = (const float*)d_in[4];
    const float* b2 = (const float*)d_in[5];
    float* out = (float*)d_out;
    const int E = in_sizes[1] / 2;     // logical edge count
    const int PB = (E + EPB - 1) / EPB;
    const int Epad = (E + 3) & ~3;
    int slabInts = (PB * NBKT + 3) & ~3;

    // workspace layout (all 16B-aligned)
    int*   slab     = (int*)d_ws;                      // PB*NBKT ints
    int*   bkt_cnt  = slab + slabInts;                 // 784 ints
    int*   bkt_off  = bkt_cnt + 784;                   // 784 ints
    int*   gflag    = bkt_off + 784;                   // 4 ints
    int*   count    = gflag + 4;                       // N ints
    int*   offs     = count + N_NODES;                 // N ints
    float* dis      = (float*)(offs + N_NODES);        // N floats
    uint*  bkt_data = (uint*)(dis + N_NODES);          // Epad uints
    int*   srcs     = (int*)(bkt_data + Epad);         // Epad ints
    uint*  y1s      = (uint*)(srcs + Epad);            // 8 slices * N*8 uints
    float* y2       = (float*)(y1s + (size_t)8 * SL_STRIDE);  // N*8 floats

    kA1    <<<PB, 256, 0, stream>>>(ei, E, slab, gflag);
    kA2a   <<<(NBKT + 3) / 4, 256, 0, stream>>>(slab, PB, bkt_cnt);
    kA2b   <<<1, 1024, 0, stream>>>(bkt_cnt, bkt_off);
    kA3    <<<PB, 256, 0, stream>>>(ei, E, gflag, slab, bkt_off, bkt_data);
    kB     <<<NBKT, 256, 0, stream>>>(bkt_data, bkt_off, bkt_cnt, srcs, count, offs, dis, y2);

    k_gemm1<<<(N_NODES + 63) / 64, 256, 0, stream>>>(x, W1, dis, y1s);
    k_agg1s<<<8 * 3125, 256, 0, stream>>>(y1s, srcs, offs, count, dis, b1, W2, y2);
    k_agg2 <<<(N_NODES * 8 + 255) / 256, 256, 0, stream>>>(y2, srcs, offs, count, dis, b2, out);
}

// Round 14
// 198.239 us; speedup vs baseline: 1.1755x; 1.1040x over previous
//
#include <hip/hip_runtime.h>

#define N_NODES 100000
#define NBKT 782              // ceil(100000/128) buckets of 128 dst nodes
#define EPB 8192              // edges per partition block
#define SL_U 400000           // uints per fp8 y1 slice = N_NODES*4 (16B rows)

typedef unsigned int uint;
typedef unsigned short ushort;
typedef __attribute__((ext_vector_type(8))) short bf16x8;   // 8 bf16 (4 VGPRs)
typedef __attribute__((ext_vector_type(4))) float f32x4;    // MFMA acc
typedef __attribute__((ext_vector_type(2))) float f32x2;    // fp8 unpack pair

union FragU { uint4 u; bf16x8 b; };

// ---------- bf16 helpers ------------------------------------------------------
__device__ __forceinline__ uint pack_bf16_2(float a, float b) {
    uint ua = __float_as_uint(a), ub = __float_as_uint(b);
    ua += 0x7fff + ((ua >> 16) & 1);           // RNE
    ub += 0x7fff + ((ub >> 16) & 1);
    return (ua >> 16) | (ub & 0xffff0000u);
}

// ---------- edge-index access (handles int32 or raw int64 little-endian) ----
__device__ __forceinline__ int edge_at(const int* __restrict__ ei, int idx, int is64) {
    return is64 ? ei[2 * idx] : ei[idx];
}

// per-block dtype probe: 1 if int64 little-endian layout (all odd words zero)
__device__ __forceinline__ int block_probe_is64(const int* __restrict__ ei, int* sh) {
    int t = threadIdx.x;
    if (t == 0) *sh = 0;
    __syncthreads();
    int any = 0;
    for (int j = t; j < 4096; j += blockDim.x) any |= ei[2 * j + 1];
    if (any) atomicOr(sh, 1);
    __syncthreads();
    return (*sh == 0);
}

// ---------- phase A1: bucket histogram -> private slab; block 0 -> gflag -----
__global__ __launch_bounds__(256) void kA1(const int* __restrict__ ei, int E,
                                           int* __restrict__ slab,
                                           int* __restrict__ gflag) {
    __shared__ int h[NBKT];
    __shared__ int shp;
    int t = threadIdx.x;
    int is64 = block_probe_is64(ei, &shp);
    if (blockIdx.x == 0 && t == 0) gflag[0] = is64 ? 0 : 1;
    for (int i = t; i < NBKT; i += 256) h[i] = 0;
    __syncthreads();
    int base = blockIdx.x * EPB;
    int end = min(base + EPB, E);
    for (int e = base + t; e < end; e += 256) {
        int d = edge_at(ei, E + e, is64);
        atomicAdd(&h[d >> 7], 1);
    }
    __syncthreads();
    for (int i = t; i < NBKT; i += 256)
        slab[(size_t)blockIdx.x * NBKT + i] = h[i];
}

// ---------- phase A2a: column prefix-scan of slab (one wave per bucket) ------
// (r10 lesson: parallelize slab traversal across CUs, never one block.)
__global__ __launch_bounds__(256) void kA2a(int* __restrict__ slab, int PB,
                                            int* __restrict__ bkt_cnt) {
    int w = threadIdx.x >> 6;                 // wave in block (0..3)
    int l = threadIdx.x & 63;                 // lane
    int k = blockIdx.x * 4 + w;               // bucket column
    if (k >= NBKT) return;
    int carry = 0;
    for (int base = 0; base < PB; base += 64) {
        int row = base + l;
        int v = (row < PB) ? slab[(size_t)row * NBKT + k] : 0;
        int incl = v;
#pragma unroll
        for (int d = 1; d < 64; d <<= 1) {
            int y = __shfl_up(incl, d, 64);
            if (l >= d) incl += y;
        }
        if (row < PB) slab[(size_t)row * NBKT + k] = carry + incl - v;  // excl
        carry += __shfl(incl, 63, 64);
    }
    if (l == 0) bkt_cnt[k] = carry;
}

// ---------- phase A2b: exclusive scan of 782 bucket counts (1 block, LDS) ----
__global__ __launch_bounds__(1024) void kA2b(const int* __restrict__ bkt_cnt,
                                             int* __restrict__ bkt_off) {
    __shared__ int s[1024];
    int t = threadIdx.x;
    int v = (t < NBKT) ? bkt_cnt[t] : 0;
    s[t] = v;
    __syncthreads();
    for (int d = 1; d < 1024; d <<= 1) {
        int y = (t >= d) ? s[t - d] : 0;
        __syncthreads();
        s[t] += y;
        __syncthreads();
    }
    if (t < NBKT) bkt_off[t] = s[t] - v;       // exclusive
}

// ---------- phase A3: single-pass partition (bases precomputed, no cursors) --
__global__ __launch_bounds__(256) void kA3(const int* __restrict__ ei, int E,
                                           const int* __restrict__ gflag,
                                           const int* __restrict__ slab,
                                           const int* __restrict__ bkt_off,
                                           uint* __restrict__ bkt_data) {
    __shared__ int h[NBKT];                   // local rank cursor
    __shared__ int pre[NBKT];                 // global base for this block
    int t = threadIdx.x;
    int is64 = (gflag[0] == 0);
    for (int i = t; i < NBKT; i += 256) {
        h[i] = 0;
        pre[i] = bkt_off[i] + slab[(size_t)blockIdx.x * NBKT + i];
    }
    __syncthreads();
    int lo = blockIdx.x * EPB;
    int end = min(lo + EPB, E);
    for (int e = lo + t; e < end; e += 256) {
        int d = edge_at(ei, E + e, is64);
        int s = edge_at(ei, e, is64);
        int b = d >> 7;
        int r = atomicAdd(&h[b], 1);
        bkt_data[pre[b] + r] = ((uint)s << 7) | (uint)(d & 127);
    }
}

// ---------- phase B: per-bucket CSR build + degrees + dis + y2 zero ----------
__global__ __launch_bounds__(256) void kB(const uint* __restrict__ bkt_data,
                                          const int* __restrict__ bkt_off,
                                          const int* __restrict__ bkt_cnt,
                                          int* __restrict__ srcs,
                                          int* __restrict__ count,
                                          int* __restrict__ offs,
                                          float* __restrict__ dis,
                                          float* __restrict__ y2) {
    __shared__ int lc[128];    // local degree
    __shared__ int sc[128];    // inclusive scan
    __shared__ int lcur[128];  // local fill cursor
    int t = threadIdx.x;
    int b = blockIdx.x;
    {
        int zb = b * 1024;
        int ze = min(zb + 1024, N_NODES * 8);
        for (int i = zb + t; i < ze; i += 256) y2[i] = 0.0f;
    }
    if (t < 128) { lc[t] = 0; lcur[t] = 0; }
    __syncthreads();
    int start = bkt_off[b];
    int n = bkt_cnt[b];
    for (int i = t; i < n; i += 256)
        atomicAdd(&lc[bkt_data[start + i] & 127], 1);
    __syncthreads();
    if (t < 128) sc[t] = lc[t];
    __syncthreads();
    for (int d = 1; d < 128; d <<= 1) {
        int y = 0;
        if (t < 128 && t >= d) y = sc[t - d];
        __syncthreads();
        if (t < 128) sc[t] += y;
        __syncthreads();
    }
    if (t < 128) {
        int node = b * 128 + t;
        if (node < N_NODES) {
            int c = lc[t];
            count[node] = c;
            offs[node] = start + sc[t] - c;
            dis[node] = rsqrtf((float)c + 1.0f);
        }
    }
    __syncthreads();
    for (int i = t; i < n; i += 256) {
        uint rec = bkt_data[start + i];
        int dl = rec & 127;
        int r = atomicAdd(&lcur[dl], 1);
        srcs[start + (sc[dl] - lc[dl]) + r] = rec >> 7;
    }
}

// ---------- GEMM1 (MFMA bf16 -> fp8 store): y1s = e4m3((x@W1)*dis), 8 slices -
// Slice = 16 cols x 1B = 16B rows (one dwordx4 gather in agg1s).
// (r12: slice must fit 4MB L2 — now 1.6MB. r9: no NT.)
__global__ __launch_bounds__(256) void k_gemm1(const float* __restrict__ x,
                                               const float* __restrict__ W,
                                               const float* __restrict__ dis,
                                               uint* __restrict__ y1s) {
    __shared__ uint4 WtA[2048];               // 32 KB
    char* wt = (char*)WtA;
    int t = threadIdx.x;

    const float4* W4 = (const float4*)W;
#pragma unroll
    for (int ii = 0; ii < 4; ++ii) {
        int tile = t + 256 * ii;              // 1024 (nq,kq) 4x4 tiles
        int nq = tile >> 5, kq = tile & 31;
        float4 r0 = W4[(4 * kq + 0) * 32 + nq];
        float4 r1 = W4[(4 * kq + 1) * 32 + nq];
        float4 r2 = W4[(4 * kq + 2) * 32 + nq];
        float4 r3 = W4[(4 * kq + 3) * 32 + nq];
        const float* p0 = (const float*)&r0;
        const float* p1 = (const float*)&r1;
        const float* p2 = (const float*)&r2;
        const float* p3 = (const float*)&r3;
#pragma unroll
        for (int cc = 0; cc < 4; ++cc) {
            int n = 4 * nq + cc;
            uint2 v;
            v.x = pack_bf16_2(p0[cc], p1[cc]);
            v.y = pack_bf16_2(p2[cc], p3[cc]);
            *(uint2*)(wt + n * 256 + (((kq >> 1) ^ (n & 7)) << 4) + ((kq & 1) << 3)) = v;
        }
    }
    __syncthreads();

    int w = t >> 6, lane = t & 63;
    int m = lane & 15, kg = lane >> 4;
    int row0 = blockIdx.x * 64 + 16 * w;

    int arow = row0 + m;
    bool av = arow < N_NODES;
    const float4* xr = (const float4*)(x + (size_t)arow * 128);
    float4 z4 = make_float4(0.f, 0.f, 0.f, 0.f);
    FragU af[4];
#pragma unroll
    for (int kf = 0; kf < 4; ++kf) {
        float4 g0 = av ? xr[8 * kf + 2 * kg]     : z4;
        float4 g1 = av ? xr[8 * kf + 2 * kg + 1] : z4;
        const float* a0 = (const float*)&g0;
        const float* a1 = (const float*)&g1;
        af[kf].u.x = pack_bf16_2(a0[0], a0[1]);
        af[kf].u.y = pack_bf16_2(a0[2], a0[3]);
        af[kf].u.z = pack_bf16_2(a1[0], a1[1]);
        af[kf].u.w = pack_bf16_2(a1[2], a1[3]);
    }

    int crow = row0 + 4 * kg;
    float dd[4];
#pragma unroll
    for (int rr = 0; rr < 4; ++rr)
        dd[rr] = (crow + rr < N_NODES) ? dis[crow + rr] : 0.0f;

    char* yb = (char*)y1s;
#pragma unroll
    for (int ct = 0; ct < 8; ++ct) {          // col-tile == slice (16 cols)
        f32x4 acc = {0.f, 0.f, 0.f, 0.f};
#pragma unroll
        for (int kf = 0; kf < 4; ++kf) {
            int n = 16 * ct + m;              // B col = lane&15
            bf16x8 bw = *(const bf16x8*)(wt + n * 256 + ((((kf << 2) | kg) ^ (n & 7)) << 4));
            acc = __builtin_amdgcn_mfma_f32_16x16x32_bf16(af[kf].b, bw, acc, 0, 0, 0);
        }
#pragma unroll
        for (int rr = 0; rr < 4; ++rr) {
            float v = acc[rr] * dd[rr];
            float p = __shfl_xor(v, 1, 64);   // partner col (odd)
            if (!(lane & 1)) {
                int grow = crow + rr;
                if (grow < N_NODES) {
                    uint pk = __builtin_amdgcn_cvt_pk_fp8_f32(v, p, 0, false);
                    *(ushort*)(yb + (size_t)ct * (SL_U * 4) + grow * 16 + m) = (ushort)pk;
                }
            }
        }
    }
}

// ---------- Aggregation 1 (8 fp8 slices, 1 dwordx4/edge) + partial GEMM2 -----
// slice = blockIdx.x % 8. 8-lane group per node, EDGE-PER-LANE.
// 13.6M gather requests (halved vs bf16). HW fp8 unpack (cvt_pk_f32_fp8).
// (r6: no deeper unroll; r9: no NT; r12: slice < 4MB L2 — 1.6MB now.)
__global__ __launch_bounds__(256) void k_agg1s(const uint* __restrict__ y1s,
                                               const int* __restrict__ srcs,
                                               const int* __restrict__ offs,
                                               const int* __restrict__ count,
                                               const float* __restrict__ dis,
                                               const float* __restrict__ b1,
                                               const float* __restrict__ W2,
                                               float* __restrict__ y2) {
    int t = threadIdx.x;
    int slice = blockIdx.x & 7;
    int nb = blockIdx.x >> 3;
    int g = t >> 3;                    // group 0..31
    int j = t & 7;                     // lane in group
    int d = nb * 32 + g;               // node (3125*32 == 100000)

    // W2 rows for this lane (fixed): rows slice*16+2j, slice*16+2j+1
    float w0[8], w1[8];
    const float* wr0 = W2 + (size_t)(slice * 16 + 2 * j) * 8;
#pragma unroll
    for (int c = 0; c < 8; ++c) { w0[c] = wr0[c]; w1[c] = wr0[8 + c]; }

    const uint4* ybase = (const uint4*)(y1s + (size_t)slice * SL_U);
    float acc[16];
#pragma unroll
    for (int c = 0; c < 16; ++c) acc[c] = 0.0f;

    int st = offs[d], n = count[d];
    for (int i = j; i <= n; i += 8) {            // i==n -> self-loop (one lane)
        int sk = d;
        if (i < n) sk = srcs[st + i];
        uint4 q = ybase[sk];                     // 16B = 16 fp8 cols
        f32x2 f0 = __builtin_amdgcn_cvt_pk_f32_fp8(q.x, false);
        f32x2 f1 = __builtin_amdgcn_cvt_pk_f32_fp8(q.x, true);
        f32x2 f2 = __builtin_amdgcn_cvt_pk_f32_fp8(q.y, false);
        f32x2 f3 = __builtin_amdgcn_cvt_pk_f32_fp8(q.y, true);
        f32x2 f4 = __builtin_amdgcn_cvt_pk_f32_fp8(q.z, false);
        f32x2 f5 = __builtin_amdgcn_cvt_pk_f32_fp8(q.z, true);
        f32x2 f6 = __builtin_amdgcn_cvt_pk_f32_fp8(q.w, false);
        f32x2 f7 = __builtin_amdgcn_cvt_pk_f32_fp8(q.w, true);
        acc[0]  += f0[0]; acc[1]  += f0[1]; acc[2]  += f1[0]; acc[3]  += f1[1];
        acc[4]  += f2[0]; acc[5]  += f2[1]; acc[6]  += f3[0]; acc[7]  += f3[1];
        acc[8]  += f4[0]; acc[9]  += f4[1]; acc[10] += f5[0]; acc[11] += f5[1];
        acc[12] += f6[0]; acc[13] += f6[1]; acc[14] += f7[0]; acc[15] += f7[1];
    }

    // reduce-scatter: lane j ends with cols 2j (v2[0]) and 2j+1 (v2[1])
    int hi4 = (j >> 2) & 1, hi2 = (j >> 1) & 1, hi1 = j & 1;
    float v8[8];
#pragma unroll
    for (int c = 0; c < 8; ++c) {
        float keep = hi4 ? acc[c + 8] : acc[c];
        float send = hi4 ? acc[c] : acc[c + 8];
        v8[c] = keep + __shfl_xor(send, 4, 8);
    }
    float v4[4];
#pragma unroll
    for (int c = 0; c < 4; ++c) {
        float keep = hi2 ? v8[c + 4] : v8[c];
        float send = hi2 ? v8[c] : v8[c + 4];
        v4[c] = keep + __shfl_xor(send, 2, 8);
    }
    float v2[2];
#pragma unroll
    for (int c = 0; c < 2; ++c) {
        float keep = hi1 ? v4[c + 2] : v4[c];
        float send = hi1 ? v4[c] : v4[c + 2];
        v2[c] = keep + __shfl_xor(send, 1, 8);
    }

    float ddv = dis[d];
    float2 b = ((const float2*)b1)[slice * 8 + j];
    float h0 = fmaxf(fmaf(v2[0], ddv, b.x), 0.0f);
    float h1 = fmaxf(fmaf(v2[1], ddv, b.y), 0.0f);

    float p[8];
#pragma unroll
    for (int c = 0; c < 8; ++c) p[c] = h0 * w0[c] + h1 * w1[c];
    float q4[4];
#pragma unroll
    for (int c = 0; c < 4; ++c) {
        float keep = hi4 ? p[c + 4] : p[c];
        float send = hi4 ? p[c] : p[c + 4];
        q4[c] = keep + __shfl_xor(send, 4, 8);
    }
    float q2[2];
#pragma unroll
    for (int c = 0; c < 2; ++c) {
        float keep = hi2 ? q4[c + 2] : q4[c];
        float send = hi2 ? q4[c] : q4[c + 2];
        q2[c] = keep + __shfl_xor(send, 2, 8);
    }
    float keep = hi1 ? q2[1] : q2[0];
    float send = hi1 ? q2[0] : q2[1];
    float q = keep + __shfl_xor(send, 1, 8);   // class j

    atomicAdd(&y2[(size_t)d * 8 + j], q * ddv);
}

// ---------- Aggregation 2 (edge-per-lane) + bias + log_softmax -> out --------
__global__ __launch_bounds__(256) void k_agg2(const float* __restrict__ y2,
                                              const int* __restrict__ srcs,
                                              const int* __restrict__ offs,
                                              const int* __restrict__ count,
                                              const float* __restrict__ dis,
                                              const float* __restrict__ b2,
                                              float* __restrict__ out) {
    int t = threadIdx.x;
    int g = (blockIdx.x * 256 + t) >> 3;   // node
    int j = t & 7;                         // lane in group
    if (g >= N_NODES) return;
    const float4* yb = (const float4*)y2;
    float acc[8];
#pragma unroll
    for (int c = 0; c < 8; ++c) acc[c] = 0.0f;
    int st = offs[g], n = count[g];
    for (int i = j; i <= n; i += 8) {          // i==n -> self term (one lane)
        int sk = g;
        if (i < n) sk = srcs[st + i];
        float4 a = yb[(size_t)sk * 2];
        float4 b = yb[(size_t)sk * 2 + 1];
        acc[0] += a.x; acc[1] += a.y; acc[2] += a.z; acc[3] += a.w;
        acc[4] += b.x; acc[5] += b.y; acc[6] += b.z; acc[7] += b.w;
    }
    int hi4 = (j >> 2) & 1, hi2 = (j >> 1) & 1, hi1 = j & 1;
    float v4[4];
#pragma unroll
    for (int c = 0; c < 4; ++c) {
        float keep = hi4 ? acc[c + 4] : acc[c];
        float send = hi4 ? acc[c] : acc[c + 4];
        v4[c] = keep + __shfl_xor(send, 4, 8);
    }
    float v2[2];
#pragma unroll
    for (int c = 0; c < 2; ++c) {
        float keep = hi2 ? v4[c + 2] : v4[c];
        float send = hi2 ? v4[c] : v4[c + 2];
        v2[c] = keep + __shfl_xor(send, 2, 8);
    }
    float keep = hi1 ? v2[1] : v2[0];
    float send = hi1 ? v2[0] : v2[1];
    float q = keep + __shfl_xor(send, 1, 8);   // class j

    float o = fmaf(q, dis[g], b2[j]);
    float m = o;
#pragma unroll
    for (int k = 1; k < 8; k <<= 1) m = fmaxf(m, __shfl_xor(m, k, 64));
    float e = expf(o - m);
    float ssum = e;
#pragma unroll
    for (int k = 1; k < 8; k <<= 1) ssum += __shfl_xor(ssum, k, 64);
    out[(size_t)g * 8 + j] = (o - m) - logf(ssum);
}

// ---------- host launcher -----------------------------------------------------
extern "C" void kernel_launch(void* const* d_in, const int* in_sizes, int n_in,
                              void* d_out, int out_size, void* d_ws, size_t ws_size,
                              hipStream_t stream) {
    const float* x  = (const float*)d_in[0];
    const int*   ei = (const int*)d_in[1];
    const float* W1 = (const float*)d_in[2];
    const float* b1 = (const float*)d_in[3];
    const float* W2 = (const float*)d_in[4];
    const float* b2 = (const float*)d_in[5];
    float* out = (float*)d_out;
    const int E = in_sizes[1] / 2;     // logical edge count
    const int PB = (E + EPB - 1) / EPB;
    const int Epad = (E + 3) & ~3;
    int slabInts = (PB * NBKT + 3) & ~3;

    // workspace layout (all 16B-aligned)
    int*   slab     = (int*)d_ws;                      // PB*NBKT ints
    int*   bkt_cnt  = slab + slabInts;                 // 784 ints
    int*   bkt_off  = bkt_cnt + 784;                   // 784 ints
    int*   gflag    = bkt_off + 784;                   // 4 ints
    int*   count    = gflag + 4;                       // N ints
    int*   offs     = count + N_NODES;                 // N ints
    float* dis      = (float*)(offs + N_NODES);        // N floats
    uint*  bkt_data = (uint*)(dis + N_NODES);          // Epad uints
    int*   srcs     = (int*)(bkt_data + Epad);         // Epad ints
    uint*  y1s      = (uint*)(srcs + Epad);            // 8 slices * N*4 uints (fp8)
    float* y2       = (float*)(y1s + (size_t)8 * SL_U);   // N*8 floats

    kA1    <<<PB, 256, 0, stream>>>(ei, E, slab, gflag);
    kA2a   <<<(NBKT + 3) / 4, 256, 0, stream>>>(slab, PB, bkt_cnt);
    kA2b   <<<1, 1024, 0, stream>>>(bkt_cnt, bkt_off);
    kA3    <<<PB, 256, 0, stream>>>(ei, E, gflag, slab, bkt_off, bkt_data);
    kB     <<<NBKT, 256, 0, stream>>>(bkt_data, bkt_off, bkt_cnt, srcs, count, offs, dis, y2);

    k_gemm1<<<(N_NODES + 63) / 64, 256, 0, stream>>>(x, W1, dis, y1s);
    k_agg1s<<<8 * 3125, 256, 0, stream>>>(y1s, srcs, offs, count, dis, b1, W2, y2);
    k_agg2 <<<(N_NODES * 8 + 255) / 256, 256, 0, stream>>>(y2, srcs, offs, count, dis, b2, out);
}

// Round 15
// 197.643 us; speedup vs baseline: 1.1791x; 1.0030x over previous
//
#include <hip/hip_runtime.h>

#define N_NODES 100000
#define NBKT 782              // ceil(100000/128) buckets of 128 dst nodes
#define EPB 8192              // edges per partition block
#define SL_U 400000           // uints per fp8 y1 slice = N_NODES*4 (16B rows)

typedef unsigned int uint;
typedef unsigned short ushort;
typedef __attribute__((ext_vector_type(8))) short bf16x8;   // 8 bf16 (4 VGPRs)
typedef __attribute__((ext_vector_type(4))) float f32x4;    // MFMA acc
typedef __attribute__((ext_vector_type(2))) float f32x2;    // fp8 unpack pair

union FragU { uint4 u; bf16x8 b; };

// ---------- bf16 helpers ------------------------------------------------------
__device__ __forceinline__ uint pack_bf16_2(float a, float b) {
    uint ua = __float_as_uint(a), ub = __float_as_uint(b);
    ua += 0x7fff + ((ua >> 16) & 1);           // RNE
    ub += 0x7fff + ((ub >> 16) & 1);
    return (ua >> 16) | (ub & 0xffff0000u);
}

// ---------- edge-index access (handles int32 or raw int64 little-endian) ----
__device__ __forceinline__ int edge_at(const int* __restrict__ ei, int idx, int is64) {
    return is64 ? ei[2 * idx] : ei[idx];
}

// per-block dtype probe: 1 if int64 little-endian layout (all odd words zero)
__device__ __forceinline__ int block_probe_is64(const int* __restrict__ ei, int* sh) {
    int t = threadIdx.x;
    if (t == 0) *sh = 0;
    __syncthreads();
    int any = 0;
    for (int j = t; j < 4096; j += blockDim.x) any |= ei[2 * j + 1];
    if (any) atomicOr(sh, 1);
    __syncthreads();
    return (*sh == 0);
}

// ---------- phase A1: bucket histogram -> private slab; block 0 -> gflag -----
__global__ __launch_bounds__(256) void kA1(const int* __restrict__ ei, int E,
                                           int* __restrict__ slab,
                                           int* __restrict__ gflag) {
    __shared__ int h[NBKT];
    __shared__ int shp;
    int t = threadIdx.x;
    int is64 = block_probe_is64(ei, &shp);
    if (blockIdx.x == 0 && t == 0) gflag[0] = is64 ? 0 : 1;
    for (int i = t; i < NBKT; i += 256) h[i] = 0;
    __syncthreads();
    int base = blockIdx.x * EPB;
    int end = min(base + EPB, E);
    for (int e = base + t; e < end; e += 256) {
        int d = edge_at(ei, E + e, is64);
        atomicAdd(&h[d >> 7], 1);
    }
    __syncthreads();
    for (int i = t; i < NBKT; i += 256)
        slab[(size_t)blockIdx.x * NBKT + i] = h[i];
}

// ---------- phase A2a: column prefix-scan of slab (one wave per bucket) ------
// (r10 lesson: parallelize slab traversal across CUs, never one block.)
__global__ __launch_bounds__(256) void kA2a(int* __restrict__ slab, int PB,
                                            int* __restrict__ bkt_cnt) {
    int w = threadIdx.x >> 6;                 // wave in block (0..3)
    int l = threadIdx.x & 63;                 // lane
    int k = blockIdx.x * 4 + w;               // bucket column
    if (k >= NBKT) return;
    int carry = 0;
    for (int base = 0; base < PB; base += 64) {
        int row = base + l;
        int v = (row < PB) ? slab[(size_t)row * NBKT + k] : 0;
        int incl = v;
#pragma unroll
        for (int d = 1; d < 64; d <<= 1) {
            int y = __shfl_up(incl, d, 64);
            if (l >= d) incl += y;
        }
        if (row < PB) slab[(size_t)row * NBKT + k] = carry + incl - v;  // excl
        carry += __shfl(incl, 63, 64);
    }
    if (l == 0) bkt_cnt[k] = carry;
}

// ---------- phase A2b: exclusive scan of 782 bucket counts (1 block, LDS) ----
__global__ __launch_bounds__(1024) void kA2b(const int* __restrict__ bkt_cnt,
                                             int* __restrict__ bkt_off) {
    __shared__ int s[1024];
    int t = threadIdx.x;
    int v = (t < NBKT) ? bkt_cnt[t] : 0;
    s[t] = v;
    __syncthreads();
    for (int d = 1; d < 1024; d <<= 1) {
        int y = (t >= d) ? s[t - d] : 0;
        __syncthreads();
        s[t] += y;
        __syncthreads();
    }
    if (t < NBKT) bkt_off[t] = s[t] - v;       // exclusive
}

// ---------- phase A3: single-pass partition (bases precomputed, no cursors) --
__global__ __launch_bounds__(256) void kA3(const int* __restrict__ ei, int E,
                                           const int* __restrict__ gflag,
                                           const int* __restrict__ slab,
                                           const int* __restrict__ bkt_off,
                                           uint* __restrict__ bkt_data) {
    __shared__ int h[NBKT];                   // local rank cursor
    __shared__ int pre[NBKT];                 // global base for this block
    int t = threadIdx.x;
    int is64 = (gflag[0] == 0);
    for (int i = t; i < NBKT; i += 256) {
        h[i] = 0;
        pre[i] = bkt_off[i] + slab[(size_t)blockIdx.x * NBKT + i];
    }
    __syncthreads();
    int lo = blockIdx.x * EPB;
    int end = min(lo + EPB, E);
    for (int e = lo + t; e < end; e += 256) {
        int d = edge_at(ei, E + e, is64);
        int s = edge_at(ei, e, is64);
        int b = d >> 7;
        int r = atomicAdd(&h[b], 1);
        bkt_data[pre[b] + r] = ((uint)s << 7) | (uint)(d & 127);
    }
}

// ---------- phase B: per-bucket CSR build + degrees + dis + y2 zero ----------
__global__ __launch_bounds__(256) void kB(const uint* __restrict__ bkt_data,
                                          const int* __restrict__ bkt_off,
                                          const int* __restrict__ bkt_cnt,
                                          int* __restrict__ srcs,
                                          int* __restrict__ count,
                                          int* __restrict__ offs,
                                          float* __restrict__ dis,
                                          float* __restrict__ y2) {
    __shared__ int lc[128];    // local degree
    __shared__ int sc[128];    // inclusive scan
    __shared__ int lcur[128];  // local fill cursor
    int t = threadIdx.x;
    int b = blockIdx.x;
    {
        int zb = b * 1024;
        int ze = min(zb + 1024, N_NODES * 8);
        for (int i = zb + t; i < ze; i += 256) y2[i] = 0.0f;
    }
    if (t < 128) { lc[t] = 0; lcur[t] = 0; }
    __syncthreads();
    int start = bkt_off[b];
    int n = bkt_cnt[b];
    for (int i = t; i < n; i += 256)
        atomicAdd(&lc[bkt_data[start + i] & 127], 1);
    __syncthreads();
    if (t < 128) sc[t] = lc[t];
    __syncthreads();
    for (int d = 1; d < 128; d <<= 1) {
        int y = 0;
        if (t < 128 && t >= d) y = sc[t - d];
        __syncthreads();
        if (t < 128) sc[t] += y;
        __syncthreads();
    }
    if (t < 128) {
        int node = b * 128 + t;
        if (node < N_NODES) {
            int c = lc[t];
            count[node] = c;
            offs[node] = start + sc[t] - c;
            dis[node] = rsqrtf((float)c + 1.0f);
        }
    }
    __syncthreads();
    for (int i = t; i < n; i += 256) {
        uint rec = bkt_data[start + i];
        int dl = rec & 127;
        int r = atomicAdd(&lcur[dl], 1);
        srcs[start + (sc[dl] - lc[dl]) + r] = rec >> 7;
    }
}

// ---------- GEMM1 (MFMA bf16 -> fp8 store): y1s = e4m3((x@W1)*dis), 8 slices -
// Slice = 16 cols x 1B = 16B rows (one dwordx4 gather in agg1s).
// (r12: slice must fit 4MB L2 — now 1.6MB. r9: no NT.)
__global__ __launch_bounds__(256) void k_gemm1(const float* __restrict__ x,
                                               const float* __restrict__ W,
                                               const float* __restrict__ dis,
                                               uint* __restrict__ y1s) {
    __shared__ uint4 WtA[2048];               // 32 KB
    char* wt = (char*)WtA;
    int t = threadIdx.x;

    const float4* W4 = (const float4*)W;
#pragma unroll
    for (int ii = 0; ii < 4; ++ii) {
        int tile = t + 256 * ii;              // 1024 (nq,kq) 4x4 tiles
        int nq = tile >> 5, kq = tile & 31;
        float4 r0 = W4[(4 * kq + 0) * 32 + nq];
        float4 r1 = W4[(4 * kq + 1) * 32 + nq];
        float4 r2 = W4[(4 * kq + 2) * 32 + nq];
        float4 r3 = W4[(4 * kq + 3) * 32 + nq];
        const float* p0 = (const float*)&r0;
        const float* p1 = (const float*)&r1;
        const float* p2 = (const float*)&r2;
        const float* p3 = (const float*)&r3;
#pragma unroll
        for (int cc = 0; cc < 4; ++cc) {
            int n = 4 * nq + cc;
            uint2 v;
            v.x = pack_bf16_2(p0[cc], p1[cc]);
            v.y = pack_bf16_2(p2[cc], p3[cc]);
            *(uint2*)(wt + n * 256 + (((kq >> 1) ^ (n & 7)) << 4) + ((kq & 1) << 3)) = v;
        }
    }
    __syncthreads();

    int w = t >> 6, lane = t & 63;
    int m = lane & 15, kg = lane >> 4;
    int row0 = blockIdx.x * 64 + 16 * w;

    int arow = row0 + m;
    bool av = arow < N_NODES;
    const float4* xr = (const float4*)(x + (size_t)arow * 128);
    float4 z4 = make_float4(0.f, 0.f, 0.f, 0.f);
    FragU af[4];
#pragma unroll
    for (int kf = 0; kf < 4; ++kf) {
        float4 g0 = av ? xr[8 * kf + 2 * kg]     : z4;
        float4 g1 = av ? xr[8 * kf + 2 * kg + 1] : z4;
        const float* a0 = (const float*)&g0;
        const float* a1 = (const float*)&g1;
        af[kf].u.x = pack_bf16_2(a0[0], a0[1]);
        af[kf].u.y = pack_bf16_2(a0[2], a0[3]);
        af[kf].u.z = pack_bf16_2(a1[0], a1[1]);
        af[kf].u.w = pack_bf16_2(a1[2], a1[3]);
    }

    int crow = row0 + 4 * kg;
    float dd[4];
#pragma unroll
    for (int rr = 0; rr < 4; ++rr)
        dd[rr] = (crow + rr < N_NODES) ? dis[crow + rr] : 0.0f;

    char* yb = (char*)y1s;
#pragma unroll
    for (int ct = 0; ct < 8; ++ct) {          // col-tile == slice (16 cols)
        f32x4 acc = {0.f, 0.f, 0.f, 0.f};
#pragma unroll
        for (int kf = 0; kf < 4; ++kf) {
            int n = 16 * ct + m;              // B col = lane&15
            bf16x8 bw = *(const bf16x8*)(wt + n * 256 + ((((kf << 2) | kg) ^ (n & 7)) << 4));
            acc = __builtin_amdgcn_mfma_f32_16x16x32_bf16(af[kf].b, bw, acc, 0, 0, 0);
        }
#pragma unroll
        for (int rr = 0; rr < 4; ++rr) {
            float v = acc[rr] * dd[rr];
            float p = __shfl_xor(v, 1, 64);   // partner col (odd)
            if (!(lane & 1)) {
                int grow = crow + rr;
                if (grow < N_NODES) {
                    uint pk = __builtin_amdgcn_cvt_pk_fp8_f32(v, p, 0, false);
                    *(ushort*)(yb + (size_t)ct * (SL_U * 4) + grow * 16 + m) = (ushort)pk;
                }
            }
        }
    }
}

// ---------- Aggregation 1 (8 fp8 slices) + partial GEMM2 ---------------------
// slice = blockIdx.x % 8. 8-lane group per node, EDGE-PER-LANE.
// 1-deep gather PREFETCH: issue load i+1, unpack/accumulate load i while it
// flies — breaks the srcs->gather->add dependent chain (r14 post-mortem:
// latency-chain bound, not request-count bound). +1 uint4 in flight (~32 VGPR,
// the 76%-occ config). (r7: do NOT go 2-deep/restructure tails; r9: no NT;
// r12: slice < 4MB L2 — 1.6MB.)
__global__ __launch_bounds__(256) void k_agg1s(const uint* __restrict__ y1s,
                                               const int* __restrict__ srcs,
                                               const int* __restrict__ offs,
                                               const int* __restrict__ count,
                                               const float* __restrict__ dis,
                                               const float* __restrict__ b1,
                                               const float* __restrict__ W2,
                                               float* __restrict__ y2) {
    int t = threadIdx.x;
    int slice = blockIdx.x & 7;
    int nb = blockIdx.x >> 3;
    int g = t >> 3;                    // group 0..31
    int j = t & 7;                     // lane in group
    int d = nb * 32 + g;               // node (3125*32 == 100000)

    // W2 rows for this lane (fixed): rows slice*16+2j, slice*16+2j+1
    float w0[8], w1[8];
    const float* wr0 = W2 + (size_t)(slice * 16 + 2 * j) * 8;
#pragma unroll
    for (int c = 0; c < 8; ++c) { w0[c] = wr0[c]; w1[c] = wr0[8 + c]; }

    const uint4* ybase = (const uint4*)(y1s + (size_t)slice * SL_U);
    float acc[16];
#pragma unroll
    for (int c = 0; c < 16; ++c) acc[c] = 0.0f;

#define ACCUM_Q(q)                                                             \
    do {                                                                       \
        f32x2 f0 = __builtin_amdgcn_cvt_pk_f32_fp8((q).x, false);              \
        f32x2 f1 = __builtin_amdgcn_cvt_pk_f32_fp8((q).x, true);               \
        f32x2 f2 = __builtin_amdgcn_cvt_pk_f32_fp8((q).y, false);              \
        f32x2 f3 = __builtin_amdgcn_cvt_pk_f32_fp8((q).y, true);               \
        f32x2 f4 = __builtin_amdgcn_cvt_pk_f32_fp8((q).z, false);              \
        f32x2 f5 = __builtin_amdgcn_cvt_pk_f32_fp8((q).z, true);               \
        f32x2 f6 = __builtin_amdgcn_cvt_pk_f32_fp8((q).w, false);              \
        f32x2 f7 = __builtin_amdgcn_cvt_pk_f32_fp8((q).w, true);               \
        acc[0]  += f0[0]; acc[1]  += f0[1]; acc[2]  += f1[0]; acc[3]  += f1[1];\
        acc[4]  += f2[0]; acc[5]  += f2[1]; acc[6]  += f3[0]; acc[7]  += f3[1];\
        acc[8]  += f4[0]; acc[9]  += f4[1]; acc[10] += f5[0]; acc[11] += f5[1];\
        acc[12] += f6[0]; acc[13] += f6[1]; acc[14] += f7[0]; acc[15] += f7[1];\
    } while (0)

    int st = offs[d], n = count[d];
    int i = j;
    if (i <= n) {                                // i==n -> self-loop (one lane)
        int sk = (i < n) ? srcs[st + i] : d;
        uint4 q = ybase[sk];
        for (i += 8; i <= n; i += 8) {
            int sk2 = (i < n) ? srcs[st + i] : d;
            uint4 qn = ybase[sk2];               // prefetch next (in flight)
            ACCUM_Q(q);                          // unpack current meanwhile
            q = qn;
        }
        ACCUM_Q(q);
    }
#undef ACCUM_Q

    // reduce-scatter: lane j ends with cols 2j (v2[0]) and 2j+1 (v2[1])
    int hi4 = (j >> 2) & 1, hi2 = (j >> 1) & 1, hi1 = j & 1;
    float v8[8];
#pragma unroll
    for (int c = 0; c < 8; ++c) {
        float keep = hi4 ? acc[c + 8] : acc[c];
        float send = hi4 ? acc[c] : acc[c + 8];
        v8[c] = keep + __shfl_xor(send, 4, 8);
    }
    float v4[4];
#pragma unroll
    for (int c = 0; c < 4; ++c) {
        float keep = hi2 ? v8[c + 4] : v8[c];
        float send = hi2 ? v8[c] : v8[c + 4];
        v4[c] = keep + __shfl_xor(send, 2, 8);
    }
    float v2[2];
#pragma unroll
    for (int c = 0; c < 2; ++c) {
        float keep = hi1 ? v4[c + 2] : v4[c];
        float send = hi1 ? v4[c] : v4[c + 2];
        v2[c] = keep + __shfl_xor(send, 1, 8);
    }

    float ddv = dis[d];
    float2 b = ((const float2*)b1)[slice * 8 + j];
    float h0 = fmaxf(fmaf(v2[0], ddv, b.x), 0.0f);
    float h1 = fmaxf(fmaf(v2[1], ddv, b.y), 0.0f);

    float p[8];
#pragma unroll
    for (int c = 0; c < 8; ++c) p[c] = h0 * w0[c] + h1 * w1[c];
    float q4[4];
#pragma unroll
    for (int c = 0; c < 4; ++c) {
        float keep = hi4 ? p[c + 4] : p[c];
        float send = hi4 ? p[c] : p[c + 4];
        q4[c] = keep + __shfl_xor(send, 4, 8);
    }
    float q2[2];
#pragma unroll
    for (int c = 0; c < 2; ++c) {
        float keep = hi2 ? q4[c + 2] : q4[c];
        float send = hi2 ? q4[c] : q4[c + 2];
        q2[c] = keep + __shfl_xor(send, 2, 8);
    }
    float keep = hi1 ? q2[1] : q2[0];
    float send = hi1 ? q2[0] : q2[1];
    float q = keep + __shfl_xor(send, 1, 8);   // class j

    atomicAdd(&y2[(size_t)d * 8 + j], q * ddv);
}

// ---------- Aggregation 2 (edge-per-lane) + bias + log_softmax -> out --------
__global__ __launch_bounds__(256) void k_agg2(const float* __restrict__ y2,
                                              const int* __restrict__ srcs,
                                              const int* __restrict__ offs,
                                              const int* __restrict__ count,
                                              const float* __restrict__ dis,
                                              const float* __restrict__ b2,
                                              float* __restrict__ out) {
    int t = threadIdx.x;
    int g = (blockIdx.x * 256 + t) >> 3;   // node
    int j = t & 7;                         // lane in group
    if (g >= N_NODES) return;
    const float4* yb = (const float4*)y2;
    float acc[8];
#pragma unroll
    for (int c = 0; c < 8; ++c) acc[c] = 0.0f;
    int st = offs[g], n = count[g];
    for (int i = j; i <= n; i += 8) {          // i==n -> self term (one lane)
        int sk = g;
        if (i < n) sk = srcs[st + i];
        float4 a = yb[(size_t)sk * 2];
        float4 b = yb[(size_t)sk * 2 + 1];
        acc[0] += a.x; acc[1] += a.y; acc[2] += a.z; acc[3] += a.w;
        acc[4] += b.x; acc[5] += b.y; acc[6] += b.z; acc[7] += b.w;
    }
    int hi4 = (j >> 2) & 1, hi2 = (j >> 1) & 1, hi1 = j & 1;
    float v4[4];
#pragma unroll
    for (int c = 0; c < 4; ++c) {
        float keep = hi4 ? acc[c + 4] : acc[c];
        float send = hi4 ? acc[c] : acc[c + 4];
        v4[c] = keep + __shfl_xor(send, 4, 8);
    }
    float v2[2];
#pragma unroll
    for (int c = 0; c < 2; ++c) {
        float keep = hi2 ? v4[c + 2] : v4[c];
        float send = hi2 ? v4[c] : v4[c + 2];
        v2[c] = keep + __shfl_xor(send, 2, 8);
    }
    float keep = hi1 ? v2[1] : v2[0];
    float send = hi1 ? v2[0] : v2[1];
    float q = keep + __shfl_xor(send, 1, 8);   // class j

    float o = fmaf(q, dis[g], b2[j]);
    float m = o;
#pragma unroll
    for (int k = 1; k < 8; k <<= 1) m = fmaxf(m, __shfl_xor(m, k, 64));
    float e = expf(o - m);
    float ssum = e;
#pragma unroll
    for (int k = 1; k < 8; k <<= 1) ssum += __shfl_xor(ssum, k, 64);
    out[(size_t)g * 8 + j] = (o - m) - logf(ssum);
}

// ---------- host launcher -----------------------------------------------------
extern "C" void kernel_launch(void* const* d_in, const int* in_sizes, int n_in,
                              void* d_out, int out_size, void* d_ws, size_t ws_size,
                              hipStream_t stream) {
    const float* x  = (const float*)d_in[0];
    const int*   ei = (const int*)d_in[1];
    const float* W1 = (const float*)d_in[2];
    const float* b1 = (const float*)d_in[3];
    const float* W2 = (const float*)d_in[4];
    const float* b2 = (const float*)d_in[5];
    float* out = (float*)d_out;
    const int E = in_sizes[1] / 2;     // logical edge count
    const int PB = (E + EPB - 1) / EPB;
    const int Epad = (E + 3) & ~3;
    int slabInts = (PB * NBKT + 3) & ~3;

    // workspace layout (all 16B-aligned)
    int*   slab     = (int*)d_ws;                      // PB*NBKT ints
    int*   bkt_cnt  = slab + slabInts;                 // 784 ints
    int*   bkt_off  = bkt_cnt + 784;                   // 784 ints
    int*   gflag    = bkt_off + 784;                   // 4 ints
    int*   count    = gflag + 4;                       // N ints
    int*   offs     = count + N_NODES;                 // N ints
    float* dis      = (float*)(offs + N_NODES);        // N floats
    uint*  bkt_data = (uint*)(dis + N_NODES);          // Epad uints
    int*   srcs     = (int*)(bkt_data + Epad);         // Epad ints
    uint*  y1s      = (uint*)(srcs + Epad);            // 8 slices * N*4 uints (fp8)
    float* y2       = (float*)(y1s + (size_t)8 * SL_U);   // N*8 floats

    kA1    <<<PB, 256, 0, stream>>>(ei, E, slab, gflag);
    kA2a   <<<(NBKT + 3) / 4, 256, 0, stream>>>(slab, PB, bkt_cnt);
    kA2b   <<<1, 1024, 0, stream>>>(bkt_cnt, bkt_off);
    kA3    <<<PB, 256, 0, stream>>>(ei, E, gflag, slab, bkt_off, bkt_data);
    kB     <<<NBKT, 256, 0, stream>>>(bkt_data, bkt_off, bkt_cnt, srcs, count, offs, dis, y2);

    k_gemm1<<<(N_NODES + 63) / 64, 256, 0, stream>>>(x, W1, dis, y1s);
    k_agg1s<<<8 * 3125, 256, 0, stream>>>(y1s, srcs, offs, count, dis, b1, W2, y2);
    k_agg2 <<<(N_NODES * 8 + 255) / 256, 256, 0, stream>>>(y2, srcs, offs, count, dis, b2, out);
}